// Round 20
// baseline (10526.561 us; speedup 1.0000x reference)
//
#include <hip/hip_runtime.h>

#define T_STEPS 2048
#define NBATCH  64
#define ISZ     256
#define HID     512
#define BH      (NBATCH*HID)   // 32768

typedef __attribute__((ext_vector_type(8))) __bf16 bf16x8;
typedef __attribute__((ext_vector_type(4))) float  f32x4;
typedef __attribute__((ext_vector_type(2))) float  f32x2;
typedef __attribute__((ext_vector_type(4))) unsigned int u32x4;

#define MFMA __builtin_amdgcn_mfma_f32_16x16x32_bf16

__device__ __forceinline__ float sigm(float v){ return 1.0f/(1.0f+expf(-v)); }

__device__ __forceinline__ unsigned int pack2(__bf16 a, __bf16 b){
    return (unsigned int)__builtin_bit_cast(unsigned short,a)
         | ((unsigned int)__builtin_bit_cast(unsigned short,b)<<16);
}

// Round-20: FULL-M geometry. 4 groups x 16 batch rows (M=16 fully used, no clamped rows)
// x 16 WGs x 32 ch = grid 64. Same 112 MFMA/WG/step now yield 2x outputs; CP exchange
// traffic and convoy population halve. Tag-in-data u64 exchange (R19). Pre-poll: first
// poll loads issue BEFORE the x-MFMA so arrival+RTT hide under compute. Eltwise: thread
// owns an adjacent ch pair -> no shfl, 1 u64 publish/thread; C lives in registers.
// Numerics = R13/R18/R19 (0.0039): x 2-way, W_ih 2-way, W_hh 2-way, h hi-only.
__global__ void __launch_bounds__(256,1)
lstm_persist(const float* __restrict__ x, const int* __restrict__ keep,
             const float* __restrict__ Wih, const float* __restrict__ Whh,
             const float* __restrict__ bih, const float* __restrict__ bhh,
             float* __restrict__ outp, unsigned long long* __restrict__ exch)
{
    __shared__ float G[4][16][32];                    // gate pre-activations
    __shared__ __align__(16) char XB[2][16][1024];    // staged x (fp32), swizzled
    __shared__ __align__(16) char HXs[16][1024];      // staged h (bf16), swizzled

    const int tid=threadIdx.x, wv=tid>>6, lane=tid&63, bid=blockIdx.x;
    const int g=bid&3, w=bid>>2, ch0=w*32, bbase=g*16;
    const int n=lane&15, lg=lane>>4;

    // exch layout: [group*2+slot][4096 u64]; u64 idx = row*256 + ch/2; 16 rows x 512 ch.

    // ---- persistent weights: 2-way splits (W_hh, W_ih) ----
    bf16x8 whh0[2][16], whh1[2][16], wih0[2][8], wih1[2][8];
    float biasv[2];
#pragma unroll
    for (int nt=0; nt<2; ++nt){
        const int row = wv*HID + ch0 + nt*16 + n;
        const float* wr = Whh + (size_t)row*HID + lg*8;
#pragma unroll
        for (int kt=0; kt<16; ++kt){
            const float* p = wr + kt*32;
            bf16x8 b0,b1;
#pragma unroll
            for(int e=0;e<8;++e){
                float f=p[e]; __bf16 hh=(__bf16)f;
                b0[e]=hh; b1[e]=(__bf16)(f-(float)hh);
            }
            whh0[nt][kt]=b0; whh1[nt][kt]=b1;
        }
        const float* wr2 = Wih + (size_t)row*ISZ + lg*8;
#pragma unroll
        for (int kt=0; kt<8; ++kt){
            const float* p = wr2 + kt*32;
            bf16x8 b0,b1;
#pragma unroll
            for(int e=0;e<8;++e){
                float f=p[e]; __bf16 hh=(__bf16)f;
                b0[e]=hh; b1[e]=(__bf16)(f-(float)hh);
            }
            wih0[nt][kt]=b0; wih1[nt][kt]=b1;
        }
        biasv[nt] = bih[row] + bhh[row];
    }

    // ---- eltwise: thread owns adjacent channel pair of one row ----
    const int erow = tid>>4, epair=(tid&15)*2;        // row 0..15, ch pair
    const int kp0 = keep[ch0+epair], kp1 = keep[ch0+epair+1];
    float c0v = 0.0f, c1v = 0.0f;                     // cell state in registers

    // ---- staging: 4 chunks/thread, rows wv+4j, col c64 ----
    const int c64 = tid&63;

    // prologue: stage x(0)
#pragma unroll
    for (int j=0;j<4;++j){
        const int r = wv + j*4;
        u32x4 q = *(const u32x4*)((const char*)x + ((size_t)(bbase+r)*ISZ)*4 + (size_t)c64*16);
        *(u32x4*)&XB[0][r][(c64^r)*16] = q;
    }
    __syncthreads();

    for (int t=0; t<T_STEPS; ++t){
        const bool hasx = (t+1<T_STEPS);
        // A: issue x(t+1) stage loads
        u32x4 xq[4];
        if (hasx){
#pragma unroll
            for (int j=0;j<4;++j){
                const int r = wv + j*4;
                xq[j] = *(const u32x4*)((const char*)x
                        + (((size_t)(t+1)*NBATCH + bbase+r)*ISZ)*4 + (size_t)c64*16);
            }
        }

        // P: pre-poll — issue first poll batch BEFORE x-MFMA (hides arrival+RTT)
        unsigned long long q64[16];
        const unsigned long long* e64 = exch + (size_t)(g*2 + ((t-1)&1))*4096;
        if (t>0){
#pragma unroll
            for (int j=0;j<4;++j){
                const int r = wv + j*4;
#pragma unroll
                for (int jj=0;jj<4;++jj)
                    q64[j*4+jj] = __hip_atomic_load(e64 + (size_t)r*256 + c64*4 + jj,
                                                    __ATOMIC_RELAXED, __HIP_MEMORY_SCOPE_AGENT);
            }
        }

        // B: x-part MFMA from LDS — x 2-way split
        f32x4 a0v[2] = {{biasv[0],biasv[0],biasv[0],biasv[0]},
                        {biasv[1],biasv[1],biasv[1],biasv[1]}};
        f32x4 a1v[2] = {{0,0,0,0},{0,0,0,0}};
#pragma unroll
        for (int kt2=0; kt2<8; ++kt2){
            f32x4 xa = *(const f32x4*)&XB[t&1][n][(((kt2*8)+lg*2+0)^n)*16];
            f32x4 xb = *(const f32x4*)&XB[t&1][n][(((kt2*8)+lg*2+1)^n)*16];
            bf16x8 a0,a1;
#pragma unroll
            for(int e=0;e<4;++e){
                float f=xa[e]; __bf16 hh=(__bf16)f;
                a0[e]=hh; a1[e]=(__bf16)(f-(float)hh);
                f=xb[e]; hh=(__bf16)f;
                a0[e+4]=hh; a1[e+4]=(__bf16)(f-(float)hh);
            }
            a0v[0]=MFMA(a0,wih0[0][kt2],a0v[0],0,0,0);
            a0v[1]=MFMA(a0,wih0[1][kt2],a0v[1],0,0,0);
            a1v[0]=MFMA(a0,wih1[0][kt2],a1v[0],0,0,0);
            a1v[1]=MFMA(a0,wih1[1][kt2],a1v[1],0,0,0);
            a1v[0]=MFMA(a1,wih0[0][kt2],a1v[0],0,0,0);   // x-lo * W_hi
            a1v[1]=MFMA(a1,wih0[1][kt2],a1v[1],0,0,0);
        }

        // C: check pre-poll; retry until all 16 tags == t
        u32x4 hq[4];
        if (t>0){
            const unsigned int need = (unsigned int)t;
            while(1){
                bool ok = true;
#pragma unroll
                for (int j=0;j<16;++j) ok &= ((unsigned int)(q64[j]>>32) == need);
                if (ok) break;
                __builtin_amdgcn_s_sleep(1);
#pragma unroll
                for (int j=0;j<4;++j){
                    const int r = wv + j*4;
#pragma unroll
                    for (int jj=0;jj<4;++jj)
                        q64[j*4+jj] = __hip_atomic_load(e64 + (size_t)r*256 + c64*4 + jj,
                                                        __ATOMIC_RELAXED, __HIP_MEMORY_SCOPE_AGENT);
                }
            }
#pragma unroll
            for (int j=0;j<4;++j){
                hq[j][0]=(unsigned int)q64[j*4+0]; hq[j][1]=(unsigned int)q64[j*4+1];
                hq[j][2]=(unsigned int)q64[j*4+2]; hq[j][3]=(unsigned int)q64[j*4+3];
            }
        }

        // E: write LDS
        if (t>0){
#pragma unroll
            for (int j=0;j<4;++j){
                const int r = wv + j*4;
                *(u32x4*)&HXs[r][(c64^r)*16] = hq[j];
            }
        }
        if (hasx){
#pragma unroll
            for (int j=0;j<4;++j){
                const int r = wv + j*4;
                *(u32x4*)&XB[(t+1)&1][r][(c64^r)*16] = xq[j];
            }
        }
        __syncthreads();

        // G: h-GEMM from LDS (h bf16 hi; W_hh 2-way split)
        if (t>0){
#pragma unroll
            for (int kt=0;kt<16;++kt){
                bf16x8 h0 = *(const bf16x8*)&HXs[n][(((kt*4)+lg)^n)*16];
                a0v[0]=MFMA(h0,whh0[0][kt],a0v[0],0,0,0);
                a0v[1]=MFMA(h0,whh0[1][kt],a0v[1],0,0,0);
                a1v[0]=MFMA(h0,whh1[0][kt],a1v[0],0,0,0);
                a1v[1]=MFMA(h0,whh1[1][kt],a1v[1],0,0,0);
            }
        }

        // H: G store — ALL 64 lanes (rows 0..15 = lg*4+r, full M). col=lane&15 (+nt*16)
#pragma unroll
        for (int nt=0; nt<2; ++nt){
            f32x4 acc = a0v[nt]+a1v[nt];
#pragma unroll
            for(int r=0;r<4;++r) G[wv][lg*4+r][nt*16+n]=acc[r];
        }
        __syncthreads();

        // J: eltwise — 2 adjacent channels per thread, C in registers
        f32x2 gi = *(const f32x2*)&G[0][erow][epair];
        f32x2 gf = *(const f32x2*)&G[1][erow][epair];
        f32x2 gg = *(const f32x2*)&G[2][erow][epair];
        f32x2 go = *(const f32x2*)&G[3][erow][epair];
        c0v = sigm(gf[0])*c0v + sigm(gi[0])*tanhf(gg[0]);
        c1v = sigm(gf[1])*c1v + sigm(gi[1])*tanhf(gg[1]);
        float h0f = sigm(go[0])*tanhf(c0v); if(!kp0) h0f=0.0f;
        float h1f = sigm(go[1])*tanhf(c1v); if(!kp1) h1f=0.0f;

        // K: publish — fire-and-forget u64 {t+1, 2xbf16}, one per thread
        {
            unsigned long long val = ((unsigned long long)(unsigned int)(t+1) << 32)
                                   | (unsigned long long)pack2((__bf16)h0f,(__bf16)h1f);
            __hip_atomic_store(exch + (size_t)(g*2+(t&1))*4096
                                    + (size_t)erow*256 + ((ch0+epair)>>1),
                               val, __ATOMIC_RELAXED, __HIP_MEMORY_SCOPE_AGENT);
        }

        // M: fp32 outputs (never read in-kernel)
        f32x2 ov; ov[0]=h0f; ov[1]=h1f;
        *(f32x2*)(outp + (size_t)t*BH + (size_t)(bbase+erow)*HID + ch0+epair) = ov;
        if (t==T_STEPS-1){
            f32x2 cv; cv[0]=c0v; cv[1]=c1v;
            *(f32x2*)(outp + (size_t)T_STEPS*BH + (size_t)(bbase+erow)*HID + ch0+epair)      = ov; // h_n
            *(f32x2*)(outp + (size_t)T_STEPS*BH + BH + (size_t)(bbase+erow)*HID + ch0+epair) = cv; // c_n
        }
    }
}

extern "C" void kernel_launch(void* const* d_in, const int* in_sizes, int n_in,
                              void* d_out, int out_size, void* d_ws, size_t ws_size,
                              hipStream_t stream)
{
    // Resolve inputs by unique element count (robust to any d_in permutation).
    const void *px = nullptr, *pk = nullptr, *pwi = nullptr, *pwh = nullptr,
               *pb0 = nullptr, *pb1 = nullptr;
    for (int i = 0; i < n_in; ++i) {
        const long s = (long)in_sizes[i];
        if      (s == (long)T_STEPS * NBATCH * ISZ) px  = d_in[i];
        else if (s == HID)                          pk  = d_in[i];
        else if (s == 4L * HID * ISZ)               pwi = d_in[i];
        else if (s == 4L * HID * HID)               pwh = d_in[i];
        else if (s == 4L * HID) { if (!pb0) pb0 = d_in[i]; else pb1 = d_in[i]; }
    }
    if (!px || !pk || !pwi || !pwh || !pb0 || !pb1) {
        px = d_in[0]; pk = d_in[1]; pwi = d_in[2]; pwh = d_in[3]; pb0 = d_in[4]; pb1 = d_in[5];
    }

    lstm_persist<<<dim3(64), dim3(256), 0, stream>>>(
        (const float*)px, (const int*)pk, (const float*)pwi, (const float*)pwh,
        (const float*)pb0, (const float*)pb1, (float*)d_out,
        (unsigned long long*)d_ws);
}

// Round 21
// 8451.586 us; speedup vs baseline: 1.2455x; 1.2455x over previous
//
#include <hip/hip_runtime.h>

#define T_STEPS 2048
#define NBATCH  64
#define ISZ     256
#define HID     512
#define BH      (NBATCH*HID)   // 32768

typedef __attribute__((ext_vector_type(8))) __bf16 bf16x8;
typedef __attribute__((ext_vector_type(4))) float  f32x4;
typedef __attribute__((ext_vector_type(2))) float  f32x2;
typedef __attribute__((ext_vector_type(4))) unsigned int u32x4;

#define MFMA __builtin_amdgcn_mfma_f32_16x16x32_bf16

__device__ __forceinline__ float sigm(float v){ return 1.0f/(1.0f+expf(-v)); }

__device__ __forceinline__ unsigned int pack2(__bf16 a, __bf16 b){
    return (unsigned int)__builtin_bit_cast(unsigned short,a)
         | ((unsigned int)__builtin_bit_cast(unsigned short,b)<<16);
}

// Round-21: full-M geometry (R20: 4 groups x 16 rows x 16 WGs x 32ch, grid 64) with the
// REGISTER-PRESSURE FIX. R20's regression (10.5ms, FETCH +186MB, busy% halved) = spill:
// weights 384 + prepoll 32 + hq 16 + xq 16 + acc 16 > ~450 line. Changes:
//   1. no pre-poll (poll after x-MFMA) -- kills 32-reg live range across MFMA block;
//   2. x written to LDS BEFORE the poll (xq dies before poll regs are born);
//   3. poll in two 8-u64 halves, each written to HXs on tag-match (no hq intermediates).
// Peak ~446 < 450. Exchange protocol (tag-in-data u64, fire-and-forget) unchanged.
// Numerics = R13/R18/R19 (0.0039): x 2-way, W_ih 2-way, W_hh 2-way, h hi-only.
__global__ void __launch_bounds__(256,1)
lstm_persist(const float* __restrict__ x, const int* __restrict__ keep,
             const float* __restrict__ Wih, const float* __restrict__ Whh,
             const float* __restrict__ bih, const float* __restrict__ bhh,
             float* __restrict__ outp, unsigned long long* __restrict__ exch)
{
    __shared__ float G[4][16][32];                    // gate pre-activations
    __shared__ __align__(16) char XB[2][16][1024];    // staged x (fp32), swizzled
    __shared__ __align__(16) char HXs[16][1024];      // staged h (bf16), swizzled

    const int tid=threadIdx.x, wv=tid>>6, lane=tid&63, bid=blockIdx.x;
    const int g=bid&3, w=bid>>2, ch0=w*32, bbase=g*16;
    const int n=lane&15, lg=lane>>4;

    // exch layout: [group*2+slot][4096 u64]; u64 idx = row*256 + ch/2 (16 rows x 512 ch).

    // ---- persistent weights: 2-way splits (W_hh, W_ih) ----
    bf16x8 whh0[2][16], whh1[2][16], wih0[2][8], wih1[2][8];
    float biasv[2];
#pragma unroll
    for (int nt=0; nt<2; ++nt){
        const int row = wv*HID + ch0 + nt*16 + n;
        const float* wr = Whh + (size_t)row*HID + lg*8;
#pragma unroll
        for (int kt=0; kt<16; ++kt){
            const float* p = wr + kt*32;
            bf16x8 b0,b1;
#pragma unroll
            for(int e=0;e<8;++e){
                float f=p[e]; __bf16 hh=(__bf16)f;
                b0[e]=hh; b1[e]=(__bf16)(f-(float)hh);
            }
            whh0[nt][kt]=b0; whh1[nt][kt]=b1;
        }
        const float* wr2 = Wih + (size_t)row*ISZ + lg*8;
#pragma unroll
        for (int kt=0; kt<8; ++kt){
            const float* p = wr2 + kt*32;
            bf16x8 b0,b1;
#pragma unroll
            for(int e=0;e<8;++e){
                float f=p[e]; __bf16 hh=(__bf16)f;
                b0[e]=hh; b1[e]=(__bf16)(f-(float)hh);
            }
            wih0[nt][kt]=b0; wih1[nt][kt]=b1;
        }
        biasv[nt] = bih[row] + bhh[row];
    }

    // ---- eltwise: thread owns adjacent channel pair of one row; C in registers ----
    const int erow = tid>>4, epair=(tid&15)*2;
    const int kp0 = keep[ch0+epair], kp1 = keep[ch0+epair+1];
    float c0v = 0.0f, c1v = 0.0f;

    const int c64 = tid&63;

    // prologue: stage x(0)
#pragma unroll
    for (int j=0;j<4;++j){
        const int r = wv + j*4;
        u32x4 q = *(const u32x4*)((const char*)x + ((size_t)(bbase+r)*ISZ)*4 + (size_t)c64*16);
        *(u32x4*)&XB[0][r][(c64^r)*16] = q;
    }
    __syncthreads();

    for (int t=0; t<T_STEPS; ++t){
        const bool hasx = (t+1<T_STEPS);
        // A: issue x(t+1) stage loads (held only until E_x, before the poll)
        u32x4 xq[4];
        if (hasx){
#pragma unroll
            for (int j=0;j<4;++j){
                const int r = wv + j*4;
                xq[j] = *(const u32x4*)((const char*)x
                        + (((size_t)(t+1)*NBATCH + bbase+r)*ISZ)*4 + (size_t)c64*16);
            }
        }

        // B: x-part MFMA from LDS — x 2-way split (48 MFMA; hides x-load latency)
        f32x4 a0v[2] = {{biasv[0],biasv[0],biasv[0],biasv[0]},
                        {biasv[1],biasv[1],biasv[1],biasv[1]}};
        f32x4 a1v[2] = {{0,0,0,0},{0,0,0,0}};
#pragma unroll
        for (int kt2=0; kt2<8; ++kt2){
            f32x4 xa = *(const f32x4*)&XB[t&1][n][(((kt2*8)+lg*2+0)^n)*16];
            f32x4 xb = *(const f32x4*)&XB[t&1][n][(((kt2*8)+lg*2+1)^n)*16];
            bf16x8 a0,a1;
#pragma unroll
            for(int e=0;e<4;++e){
                float f=xa[e]; __bf16 hh=(__bf16)f;
                a0[e]=hh; a1[e]=(__bf16)(f-(float)hh);
                f=xb[e]; hh=(__bf16)f;
                a0[e+4]=hh; a1[e+4]=(__bf16)(f-(float)hh);
            }
            a0v[0]=MFMA(a0,wih0[0][kt2],a0v[0],0,0,0);
            a0v[1]=MFMA(a0,wih0[1][kt2],a0v[1],0,0,0);
            a1v[0]=MFMA(a0,wih1[0][kt2],a1v[0],0,0,0);
            a1v[1]=MFMA(a0,wih1[1][kt2],a1v[1],0,0,0);
            a1v[0]=MFMA(a1,wih0[0][kt2],a1v[0],0,0,0);   // x-lo * W_hi
            a1v[1]=MFMA(a1,wih0[1][kt2],a1v[1],0,0,0);
        }

        // E_x: retire xq into LDS NOW (frees 16 VGPRs before poll regs go live).
        // Safe: XB[(t+1)&1]'s last readers were B(t-1), two barriers ago.
        if (hasx){
#pragma unroll
            for (int j=0;j<4;++j){
                const int r = wv + j*4;
                *(u32x4*)&XB[(t+1)&1][r][(c64^r)*16] = xq[j];
            }
        }

        // C: poll exchange in TWO HALVES of 8 u64 (16 VGPRs live each, not 32+16)
        if (t>0){
            const unsigned int need = (unsigned int)t;
            const unsigned long long* e64 = exch + (size_t)(g*2 + ((t-1)&1))*4096;
#pragma unroll
            for (int half=0; half<2; ++half){
                const int r0 = wv + half*8;       // rows r0 and r0+4
                const int r1 = r0 + 4;
                unsigned long long q[8];
                while(1){
#pragma unroll
                    for (int jj=0;jj<4;++jj){
                        q[jj]   = __hip_atomic_load(e64 + (size_t)r0*256 + c64*4 + jj,
                                                    __ATOMIC_RELAXED, __HIP_MEMORY_SCOPE_AGENT);
                        q[4+jj] = __hip_atomic_load(e64 + (size_t)r1*256 + c64*4 + jj,
                                                    __ATOMIC_RELAXED, __HIP_MEMORY_SCOPE_AGENT);
                    }
                    bool ok = true;
#pragma unroll
                    for (int jj=0;jj<8;++jj) ok &= ((unsigned int)(q[jj]>>32) == need);
                    if (ok) break;
                    __builtin_amdgcn_s_sleep(1);
                }
                u32x4 d0, d1;
#pragma unroll
                for (int jj=0;jj<4;++jj){ d0[jj]=(unsigned int)q[jj]; d1[jj]=(unsigned int)q[4+jj]; }
                *(u32x4*)&HXs[r0][(c64^r0)*16] = d0;
                *(u32x4*)&HXs[r1][(c64^r1)*16] = d1;
            }
        }
        __syncthreads();

        // G: h-GEMM from LDS (h bf16 hi; W_hh 2-way split; 64 MFMA)
        if (t>0){
#pragma unroll
            for (int kt=0;kt<16;++kt){
                bf16x8 h0 = *(const bf16x8*)&HXs[n][(((kt*4)+lg)^n)*16];
                a0v[0]=MFMA(h0,whh0[0][kt],a0v[0],0,0,0);
                a0v[1]=MFMA(h0,whh0[1][kt],a0v[1],0,0,0);
                a1v[0]=MFMA(h0,whh1[0][kt],a1v[0],0,0,0);
                a1v[1]=MFMA(h0,whh1[1][kt],a1v[1],0,0,0);
            }
        }

        // H: G store — all 64 lanes (full M=16: row=lg*4+r, col=nt*16+n)
#pragma unroll
        for (int nt=0; nt<2; ++nt){
            f32x4 acc = a0v[nt]+a1v[nt];
#pragma unroll
            for(int r=0;r<4;++r) G[wv][lg*4+r][nt*16+n]=acc[r];
        }
        __syncthreads();

        // J: eltwise — 2 adjacent channels per thread, C in registers
        f32x2 gi = *(const f32x2*)&G[0][erow][epair];
        f32x2 gf = *(const f32x2*)&G[1][erow][epair];
        f32x2 gg = *(const f32x2*)&G[2][erow][epair];
        f32x2 go = *(const f32x2*)&G[3][erow][epair];
        c0v = sigm(gf[0])*c0v + sigm(gi[0])*tanhf(gg[0]);
        c1v = sigm(gf[1])*c1v + sigm(gi[1])*tanhf(gg[1]);
        float h0f = sigm(go[0])*tanhf(c0v); if(!kp0) h0f=0.0f;
        float h1f = sigm(go[1])*tanhf(c1v); if(!kp1) h1f=0.0f;

        // K: publish — fire-and-forget u64 {t+1, 2xbf16}, one per thread
        {
            unsigned long long val = ((unsigned long long)(unsigned int)(t+1) << 32)
                                   | (unsigned long long)pack2((__bf16)h0f,(__bf16)h1f);
            __hip_atomic_store(exch + (size_t)(g*2+(t&1))*4096
                                    + (size_t)erow*256 + ((ch0+epair)>>1),
                               val, __ATOMIC_RELAXED, __HIP_MEMORY_SCOPE_AGENT);
        }

        // M: fp32 outputs (never read in-kernel)
        f32x2 ov; ov[0]=h0f; ov[1]=h1f;
        *(f32x2*)(outp + (size_t)t*BH + (size_t)(bbase+erow)*HID + ch0+epair) = ov;
        if (t==T_STEPS-1){
            f32x2 cv; cv[0]=c0v; cv[1]=c1v;
            *(f32x2*)(outp + (size_t)T_STEPS*BH + (size_t)(bbase+erow)*HID + ch0+epair)      = ov; // h_n
            *(f32x2*)(outp + (size_t)T_STEPS*BH + BH + (size_t)(bbase+erow)*HID + ch0+epair) = cv; // c_n
        }
    }
}

extern "C" void kernel_launch(void* const* d_in, const int* in_sizes, int n_in,
                              void* d_out, int out_size, void* d_ws, size_t ws_size,
                              hipStream_t stream)
{
    // Resolve inputs by unique element count (robust to any d_in permutation).
    const void *px = nullptr, *pk = nullptr, *pwi = nullptr, *pwh = nullptr,
               *pb0 = nullptr, *pb1 = nullptr;
    for (int i = 0; i < n_in; ++i) {
        const long s = (long)in_sizes[i];
        if      (s == (long)T_STEPS * NBATCH * ISZ) px  = d_in[i];
        else if (s == HID)                          pk  = d_in[i];
        else if (s == 4L * HID * ISZ)               pwi = d_in[i];
        else if (s == 4L * HID * HID)               pwh = d_in[i];
        else if (s == 4L * HID) { if (!pb0) pb0 = d_in[i]; else pb1 = d_in[i]; }
    }
    if (!px || !pk || !pwi || !pwh || !pb0 || !pb1) {
        px = d_in[0]; pk = d_in[1]; pwi = d_in[2]; pwh = d_in[3]; pb0 = d_in[4]; pb1 = d_in[5];
    }

    lstm_persist<<<dim3(64), dim3(256), 0, stream>>>(
        (const float*)px, (const int*)pk, (const float*)pwi, (const float*)pwh,
        (const float*)pb0, (const float*)pb1, (float*)d_out,
        (unsigned long long*)d_ws);
}